// Round 2
// baseline (738.886 us; speedup 1.0000x reference)
//
#include <hip/hip_runtime.h>

// Banded (sliding-window) attention scores, f32.
// out[bh][t][r] = sum_d q[bh][t][d] * k[bh][t + r - 63][d], zero-padded in t.
// B*H = 128, T = 4096, D = 64, R = 127.
//
// Structure: one block = one (bh, 128-row t-tile). Skewed outer-product
// register tiling: thread owns 8 t x 8 r outputs; k rows needed are
// s_local = t_local + r -> 15 contiguous LDS rows -> 4x ds_read_b128.
// LDS stages q^T [d][t] and k^T [d][s] in d-chunks of 32 (49 KB -> 3 blocks/CU).
//
// (Round 1: resubmission of round-0 kernel — previous bench was an
// infrastructure failure, no counters; need the baseline measurement.)

namespace {
constexpr int kT_ = 4096;   // sequence length
constexpr int kD = 64;      // head dim
constexpr int kR = 127;     // band width (restrict)
constexpr int kHalf = 63;   // restrict / 2
constexpr int kBH = 128;    // B*H
constexpr int TT = 128;     // t rows per block
constexpr int SSpan = 254;  // staged k rows: TT + kR - 1
constexpr int SLds = 256;   // padded LDS k row count
constexpr int DC = 32;      // d chunk staged per barrier
constexpr int QPAD = 4;
constexpr int KPAD = 4;
}  // namespace

__global__ __launch_bounds__(256, 3)
void banded_scores_f32(const float* __restrict__ q,
                       const float* __restrict__ k,
                       float* __restrict__ out) {
  __shared__ float qT[DC][TT + QPAD];    // 32 x 132 f32 = 16.5 KB
  __shared__ float kTs[DC][SLds + KPAD]; // 32 x 260 f32 = 32.5 KB

  const int tb = blockIdx.x;   // t-tile index [0, 32)
  const int bh = blockIdx.y;   // [0, 128)
  const int t0 = tb * TT;
  const int tid = threadIdx.x;
  const int r0 = (tid & 15) * 8;   // this thread's first r
  const int tq = (tid >> 4) * 8;   // this thread's first t (local)
  const int kb = tq + r0;          // first k row (local, s_local = t_local + r)

  const float* __restrict__ qbh = q + (size_t)bh * kT_ * kD;
  const float* __restrict__ kbh = k + (size_t)bh * kT_ * kD;

  float acc[8][8];
#pragma unroll
  for (int i = 0; i < 8; ++i)
#pragma unroll
    for (int j = 0; j < 8; ++j) acc[i][j] = 0.0f;

#pragma unroll
  for (int c = 0; c < kD / DC; ++c) {
    const int dbase = c * DC;
    __syncthreads();  // previous chunk's compute done before overwrite

    // ---- stage q^T chunk [DC][TT]: 1024 float4, 4 per thread ----
#pragma unroll
    for (int n = 0; n < (TT * DC) / 4 / 256; ++n) {
      const int idx = tid + 256 * n;
      const int tl = idx >> 3;          // t local [0,128)
      const int dl = (idx & 7) * 4;     // d local {0,4,...,28}
      const float4 v = *reinterpret_cast<const float4*>(
          &qbh[(t0 + tl) * kD + dbase + dl]);
      qT[dl + 0][tl] = v.x;
      qT[dl + 1][tl] = v.y;
      qT[dl + 2][tl] = v.z;
      qT[dl + 3][tl] = v.w;
    }

    // ---- stage k^T chunk [DC][SSpan], zero outside [0, T) ----
#pragma unroll
    for (int n = 0; n < 8; ++n) {
      const int idx = tid + 256 * n;
      const int sl = idx >> 3;          // s local [0,254)
      const int dl = (idx & 7) * 4;
      if (sl < SSpan) {
        const int s = t0 - kHalf + sl;  // global k row
        float4 v = make_float4(0.f, 0.f, 0.f, 0.f);
        if (s >= 0 && s < kT_)
          v = *reinterpret_cast<const float4*>(&kbh[s * kD + dbase + dl]);
        kTs[dl + 0][sl] = v.x;
        kTs[dl + 1][sl] = v.y;
        kTs[dl + 2][sl] = v.z;
        kTs[dl + 3][sl] = v.w;
      }
    }
    __syncthreads();

    // ---- compute: 64 FMA per d-step per thread ----
#pragma unroll 8
    for (int d = 0; d < DC; ++d) {
      const float4 qa = *reinterpret_cast<const float4*>(&qT[d][tq]);
      const float4 qb = *reinterpret_cast<const float4*>(&qT[d][tq + 4]);
      const float4 k0 = *reinterpret_cast<const float4*>(&kTs[d][kb]);
      const float4 k1 = *reinterpret_cast<const float4*>(&kTs[d][kb + 4]);
      const float4 k2 = *reinterpret_cast<const float4*>(&kTs[d][kb + 8]);
      const float4 k3 = *reinterpret_cast<const float4*>(&kTs[d][kb + 12]);
      const float qv[8] = {qa.x, qa.y, qa.z, qa.w, qb.x, qb.y, qb.z, qb.w};
      const float kv[16] = {k0.x, k0.y, k0.z, k0.w, k1.x, k1.y, k1.z, k1.w,
                            k2.x, k2.y, k2.z, k2.w, k3.x, k3.y, k3.z, k3.w};
#pragma unroll
      for (int i = 0; i < 8; ++i)
#pragma unroll
        for (int j = 0; j < 8; ++j) acc[i][j] += qv[i] * kv[i + j];
    }
  }

  // ---- store: 8 rows x 8 contiguous r (mask r == 127) ----
  float* __restrict__ obh = out + (size_t)bh * kT_ * kR;
#pragma unroll
  for (int i = 0; i < 8; ++i) {
    const int t = t0 + tq + i;
    float* orow = obh + (size_t)t * kR + r0;
#pragma unroll
    for (int j = 0; j < 8; ++j) {
      if (r0 + j < kR) orow[j] = acc[i][j];
    }
  }
}

extern "C" void kernel_launch(void* const* d_in, const int* in_sizes, int n_in,
                              void* d_out, int out_size, void* d_ws, size_t ws_size,
                              hipStream_t stream) {
  const float* q = (const float*)d_in[0];
  const float* k = (const float*)d_in[1];
  // d_in[2] is the python scalar `restrict` (= 127); geometry is compile-time.
  float* out = (float*)d_out;
  dim3 grid(kT_ / TT, kBH);
  banded_scores_f32<<<grid, 256, 0, stream>>>(q, k, out);
}